// Round 1
// baseline (852.758 us; speedup 1.0000x reference)
//
#include <hip/hip_runtime.h>

// Problem constants (from reference)
#define N_NODES  100000
#define D_DIM    16
#define NFILT    8
#define NNZ_CNT  1600000

// w_wav[n,f] = t^(2^f) - t^(2^(f+1)),  t = exp(-eig[n]); exact repeated squaring
__global__ void wav_kernel(const float* __restrict__ eig, float* __restrict__ w_wav) {
    int n = blockIdx.x * blockDim.x + threadIdx.x;
    if (n >= N_NODES) return;
    float cur = expf(-eig[n]);   // t^1
    float w[NFILT];
#pragma unroll
    for (int f = 0; f < NFILT; ++f) {
        float nx = cur * cur;    // t^(2^(f+1))
        w[f] = cur - nx;
        cur = nx;
    }
    float4* p = (float4*)(w_wav + (size_t)n * NFILT);
    p[0] = make_float4(w[0], w[1], w[2], w[3]);
    p[1] = make_float4(w[4], w[5], w[6], w[7]);
}

// Pass 1: LTx[c,d] += v[e] * x[r,d]   (16 threads per edge)
__global__ void scatter1_kernel(const float* __restrict__ x,
                                const int* __restrict__ rows,
                                const int* __restrict__ cols,
                                const float* __restrict__ v,
                                float* __restrict__ LTx) {
    long long idx = (long long)blockIdx.x * blockDim.x + threadIdx.x;
    if (idx >= (long long)NNZ_CNT * D_DIM) return;
    int e = (int)(idx >> 4);
    int d = (int)(idx & 15);
    int r = rows[e];
    int c = cols[e];
    float val = v[e] * x[(size_t)r * D_DIM + d];
    atomicAdd(LTx + (size_t)c * D_DIM + d, val);
}

// Pass 2: out[r, k] += v[e] * LTx[c, k>>3] * w_wav[c, k&7]   (128 threads per edge)
__global__ void scatter2_kernel(const int* __restrict__ rows,
                                const int* __restrict__ cols,
                                const float* __restrict__ v,
                                const float* __restrict__ LTx,
                                const float* __restrict__ w_wav,
                                float* __restrict__ out) {
    long long idx = (long long)blockIdx.x * blockDim.x + threadIdx.x;
    if (idx >= (long long)NNZ_CNT * (D_DIM * NFILT)) return;
    int e = (int)(idx >> 7);
    int k = (int)(idx & 127);
    int r = rows[e];
    int c = cols[e];
    float g = LTx[(size_t)c * D_DIM + (k >> 3)] * w_wav[(size_t)c * NFILT + (k & 7)];
    atomicAdd(out + (size_t)r * (D_DIM * NFILT) + k, v[e] * g);
}

extern "C" void kernel_launch(void* const* d_in, const int* in_sizes, int n_in,
                              void* d_out, int out_size, void* d_ws, size_t ws_size,
                              hipStream_t stream) {
    const float* x      = (const float*)d_in[0];
    const int*   L_rows = (const int*)  d_in[1];
    const int*   L_cols = (const int*)  d_in[2];
    const float* L_v    = (const float*)d_in[3];
    const float* eig    = (const float*)d_in[4];
    float* out = (float*)d_out;

    float* LTx   = (float*)d_ws;                       // [N, 16]  = 6.4 MB
    float* w_wav = LTx + (size_t)N_NODES * D_DIM;      // [N, 8]   = 3.2 MB

    // d_out / d_ws are poisoned (0xAA) before every timed call — zero what we accumulate into.
    hipMemsetAsync(d_out, 0, (size_t)out_size * sizeof(float), stream);
    hipMemsetAsync(LTx, 0, (size_t)N_NODES * D_DIM * sizeof(float), stream);

    wav_kernel<<<(N_NODES + 255) / 256, 256, 0, stream>>>(eig, w_wav);

    {
        long long total = (long long)NNZ_CNT * D_DIM;           // 25.6M
        int grid = (int)((total + 255) / 256);
        scatter1_kernel<<<grid, 256, 0, stream>>>(x, L_rows, L_cols, L_v, LTx);
    }
    {
        long long total = (long long)NNZ_CNT * (D_DIM * NFILT); // 204.8M
        int grid = (int)((total + 255) / 256);
        scatter2_kernel<<<grid, 256, 0, stream>>>(L_rows, L_cols, L_v, LTx, w_wav, out);
    }
}

// Round 2
// 614.974 us; speedup vs baseline: 1.3867x; 1.3867x over previous
//
#include <hip/hip_runtime.h>

#define N_NODES   100000
#define D_DIM     16
#define NFILT     8
#define KOUT      (D_DIM * NFILT)   // 128
#define NNZ_CNT   1600000

#define SCAN_BLOCK 512
#define SCAN_NBLK  ((N_NODES + SCAN_BLOCK - 1) / SCAN_BLOCK)   // 196

// w_wav[n,f] = t^(2^f) - t^(2^(f+1)),  t = exp(-eig[n]); exact repeated squaring
__global__ void wav_kernel(const float* __restrict__ eig, float* __restrict__ w_wav) {
    int n = blockIdx.x * blockDim.x + threadIdx.x;
    if (n >= N_NODES) return;
    float cur = expf(-eig[n]);
    float w[NFILT];
#pragma unroll
    for (int f = 0; f < NFILT; ++f) {
        float nx = cur * cur;
        w[f] = cur - nx;
        cur = nx;
    }
    float4* p = (float4*)(w_wav + (size_t)n * NFILT);
    p[0] = make_float4(w[0], w[1], w[2], w[3]);
    p[1] = make_float4(w[4], w[5], w[6], w[7]);
}

// Pass 1: LTx[c,d] += v[e] * x[r,d]   (16 threads per edge, atomic; LTx is 6.4MB L2-resident)
__global__ void scatter1_kernel(const float* __restrict__ x,
                                const int* __restrict__ rows,
                                const int* __restrict__ cols,
                                const float* __restrict__ v,
                                float* __restrict__ LTx) {
    long long idx = (long long)blockIdx.x * blockDim.x + threadIdx.x;
    if (idx >= (long long)NNZ_CNT * D_DIM) return;
    int e = (int)(idx >> 4);
    int d = (int)(idx & 15);
    int r = rows[e];
    int c = cols[e];
    float val = v[e] * x[(size_t)r * D_DIM + d];
    atomicAdd(LTx + (size_t)c * D_DIM + d, val);
}

// --- CSR build: histogram + 2-level exclusive scan + permute ---

__global__ void hist_kernel(const int* __restrict__ rows, int* __restrict__ counts) {
    int e = blockIdx.x * blockDim.x + threadIdx.x;
    if (e >= NNZ_CNT) return;
    atomicAdd(&counts[rows[e]], 1);
}

// per-block inclusive scan -> write exclusive (block-local) + block total
__global__ void scan1_kernel(const int* __restrict__ counts,
                             int* __restrict__ offsets,
                             int* __restrict__ blocksums) {
    __shared__ int s[SCAN_BLOCK];
    int tid = threadIdx.x;
    int i = blockIdx.x * SCAN_BLOCK + tid;
    int v = (i < N_NODES) ? counts[i] : 0;
    s[tid] = v;
    __syncthreads();
    for (int off = 1; off < SCAN_BLOCK; off <<= 1) {
        int t = (tid >= off) ? s[tid - off] : 0;
        __syncthreads();
        s[tid] += t;
        __syncthreads();
    }
    if (i < N_NODES) offsets[i] = s[tid] - v;   // block-local exclusive
    if (tid == SCAN_BLOCK - 1) blocksums[blockIdx.x] = s[tid];
}

// single block: exclusive scan of block sums (NBLK <= 256)
__global__ void scan2_kernel(const int* __restrict__ blocksums, int* __restrict__ blockoffs) {
    __shared__ int s[256];
    int tid = threadIdx.x;
    int v = (tid < SCAN_NBLK) ? blocksums[tid] : 0;
    s[tid] = v;
    __syncthreads();
    for (int off = 1; off < 256; off <<= 1) {
        int t = (tid >= off) ? s[tid - off] : 0;
        __syncthreads();
        s[tid] += t;
        __syncthreads();
    }
    if (tid < SCAN_NBLK) blockoffs[tid] = s[tid] - v;
}

// add block offsets; also init cursor and the sentinel offsets[N] = NNZ
__global__ void scan3_kernel(int* __restrict__ offsets,
                             const int* __restrict__ blockoffs,
                             int* __restrict__ cursor) {
    int i = blockIdx.x * SCAN_BLOCK + threadIdx.x;
    if (i == 0) offsets[N_NODES] = NNZ_CNT;
    if (i >= N_NODES) return;
    int off = offsets[i] + blockoffs[blockIdx.x];
    offsets[i] = off;
    cursor[i] = off;
}

// permute edges into row-grouped order (order within a row is arbitrary — sum commutes)
__global__ void permute_kernel(const int* __restrict__ rows,
                               const int* __restrict__ cols,
                               const float* __restrict__ v,
                               int* __restrict__ cursor,
                               int* __restrict__ sc,
                               float* __restrict__ sv) {
    int e = blockIdx.x * blockDim.x + threadIdx.x;
    if (e >= NNZ_CNT) return;
    int r = rows[e];
    int pos = atomicAdd(&cursor[r], 1);
    sc[pos] = cols[e];
    sv[pos] = v[e];
}

// Pass 2 as gather: out[r, d*8+f] = sum over edges of row r: v * LTx[c,d] * wav[c,f]
// 128 threads per row (2 waves); edge data broadcast within wave, one store per output.
__global__ void gather2_kernel(const int* __restrict__ offsets,
                               const int* __restrict__ sc,
                               const float* __restrict__ sv,
                               const float* __restrict__ LTx,
                               const float* __restrict__ wav,
                               float* __restrict__ out) {
    long long t = (long long)blockIdx.x * blockDim.x + threadIdx.x;
    if (t >= (long long)N_NODES * KOUT) return;
    int r = (int)(t >> 7);
    int k = (int)(t & 127);
    int d = k >> 3;
    int f = k & 7;
    int start = offsets[r];
    int end = offsets[r + 1];
    float acc = 0.f;
    for (int i = start; i < end; ++i) {
        int c = sc[i];
        float v = sv[i];
        acc += v * LTx[(size_t)c * D_DIM + d] * wav[(size_t)c * NFILT + f];
    }
    out[(size_t)r * KOUT + k] = acc;
}

extern "C" void kernel_launch(void* const* d_in, const int* in_sizes, int n_in,
                              void* d_out, int out_size, void* d_ws, size_t ws_size,
                              hipStream_t stream) {
    const float* x      = (const float*)d_in[0];
    const int*   L_rows = (const int*)  d_in[1];
    const int*   L_cols = (const int*)  d_in[2];
    const float* L_v    = (const float*)d_in[3];
    const float* eig    = (const float*)d_in[4];
    float* out = (float*)d_out;

    // workspace layout (all 4-byte elements, ~23.7 MB total)
    float* LTx       = (float*)d_ws;                       // [N*16]
    float* wav       = LTx + (size_t)N_NODES * D_DIM;      // [N*8]
    int*   counts    = (int*)(wav + (size_t)N_NODES * NFILT); // [N]
    int*   offsets   = counts + N_NODES;                   // [N+1]
    int*   cursor    = offsets + N_NODES + 1;              // [N]
    int*   blocksums = cursor + N_NODES;                   // [256]
    int*   blockoffs = blocksums + 256;                    // [256]
    int*   sc        = blockoffs + 256;                    // [NNZ]
    float* sv        = (float*)(sc + NNZ_CNT);             // [NNZ]

    // zero the accumulators (ws is re-poisoned 0xAA before each call)
    hipMemsetAsync(LTx, 0, (size_t)N_NODES * D_DIM * sizeof(float), stream);
    hipMemsetAsync(counts, 0, (size_t)N_NODES * sizeof(int), stream);

    wav_kernel<<<(N_NODES + 255) / 256, 256, 0, stream>>>(eig, wav);

    // CSR build (by row)
    hist_kernel<<<(NNZ_CNT + 255) / 256, 256, 0, stream>>>(L_rows, counts);
    scan1_kernel<<<SCAN_NBLK, SCAN_BLOCK, 0, stream>>>(counts, offsets, blocksums);
    scan2_kernel<<<1, 256, 0, stream>>>(blocksums, blockoffs);
    scan3_kernel<<<SCAN_NBLK, SCAN_BLOCK, 0, stream>>>(offsets, blockoffs, cursor);
    permute_kernel<<<(NNZ_CNT + 255) / 256, 256, 0, stream>>>(L_rows, L_cols, L_v, cursor, sc, sv);

    // Pass 1 (atomic scatter into L2-resident 6.4MB LTx)
    {
        long long total = (long long)NNZ_CNT * D_DIM;
        scatter1_kernel<<<(int)((total + 255) / 256), 256, 0, stream>>>(x, L_rows, L_cols, L_v, LTx);
    }

    // Pass 2 (gather, no atomics)
    {
        long long total = (long long)N_NODES * KOUT;   // 12.8M
        gather2_kernel<<<(int)((total + 255) / 256), 256, 0, stream>>>(offsets, sc, sv, LTx, wav, out);
    }
}

// Round 3
// 427.213 us; speedup vs baseline: 1.9961x; 1.4395x over previous
//
#include <hip/hip_runtime.h>

#define N_NODES   100000
#define D_DIM     16
#define NFILT     8
#define KOUT      (D_DIM * NFILT)   // 128
#define NNZ_CNT   1600000

#define SCAN_BLOCK 512
#define SCAN_NBLK  ((N_NODES + SCAN_BLOCK - 1) / SCAN_BLOCK)   // 196

// w_wav[n,f] = t^(2^f) - t^(2^(f+1)),  t = exp(-eig[n]); exact repeated squaring
__global__ void wav_kernel(const float* __restrict__ eig, float* __restrict__ w_wav) {
    int n = blockIdx.x * blockDim.x + threadIdx.x;
    if (n >= N_NODES) return;
    float cur = expf(-eig[n]);
    float w[NFILT];
#pragma unroll
    for (int f = 0; f < NFILT; ++f) {
        float nx = cur * cur;
        w[f] = cur - nx;
        cur = nx;
    }
    float4* p = (float4*)(w_wav + (size_t)n * NFILT);
    p[0] = make_float4(w[0], w[1], w[2], w[3]);
    p[1] = make_float4(w[4], w[5], w[6], w[7]);
}

// Pass 1: LTx[c,d] += v[e] * x[r,d]   (16 threads per edge; LTx is 6.4MB, L2-resident)
__global__ void scatter1_kernel(const float* __restrict__ x,
                                const int* __restrict__ rows,
                                const int* __restrict__ cols,
                                const float* __restrict__ v,
                                float* __restrict__ LTx) {
    long long idx = (long long)blockIdx.x * blockDim.x + threadIdx.x;
    if (idx >= (long long)NNZ_CNT * D_DIM) return;
    int e = (int)(idx >> 4);
    int d = (int)(idx & 15);
    int r = rows[e];
    int c = cols[e];
    float val = v[e] * x[(size_t)r * D_DIM + d];
    atomicAdd(LTx + (size_t)c * D_DIM + d, val);
}

// --- CSR build: histogram + 2-level exclusive scan + permute ---

__global__ void hist_kernel(const int* __restrict__ rows, int* __restrict__ counts) {
    int e = blockIdx.x * blockDim.x + threadIdx.x;
    if (e >= NNZ_CNT) return;
    atomicAdd(&counts[rows[e]], 1);
}

__global__ void scan1_kernel(const int* __restrict__ counts,
                             int* __restrict__ offsets,
                             int* __restrict__ blocksums) {
    __shared__ int s[SCAN_BLOCK];
    int tid = threadIdx.x;
    int i = blockIdx.x * SCAN_BLOCK + tid;
    int v = (i < N_NODES) ? counts[i] : 0;
    s[tid] = v;
    __syncthreads();
    for (int off = 1; off < SCAN_BLOCK; off <<= 1) {
        int t = (tid >= off) ? s[tid - off] : 0;
        __syncthreads();
        s[tid] += t;
        __syncthreads();
    }
    if (i < N_NODES) offsets[i] = s[tid] - v;
    if (tid == SCAN_BLOCK - 1) blocksums[blockIdx.x] = s[tid];
}

__global__ void scan2_kernel(const int* __restrict__ blocksums, int* __restrict__ blockoffs) {
    __shared__ int s[256];
    int tid = threadIdx.x;
    int v = (tid < SCAN_NBLK) ? blocksums[tid] : 0;
    s[tid] = v;
    __syncthreads();
    for (int off = 1; off < 256; off <<= 1) {
        int t = (tid >= off) ? s[tid - off] : 0;
        __syncthreads();
        s[tid] += t;
        __syncthreads();
    }
    if (tid < SCAN_NBLK) blockoffs[tid] = s[tid] - v;
}

__global__ void scan3_kernel(int* __restrict__ offsets,
                             const int* __restrict__ blockoffs,
                             int* __restrict__ cursor) {
    int i = blockIdx.x * SCAN_BLOCK + threadIdx.x;
    if (i == 0) offsets[N_NODES] = NNZ_CNT;
    if (i >= N_NODES) return;
    int off = offsets[i] + blockoffs[blockIdx.x];
    offsets[i] = off;
    cursor[i] = off;
}

// permute edges into row-grouped order; one packed 8B record per edge (halves random line touches)
__global__ void permute_kernel(const int* __restrict__ rows,
                               const int* __restrict__ cols,
                               const float* __restrict__ v,
                               int* __restrict__ cursor,
                               int2* __restrict__ ep) {
    int e = blockIdx.x * blockDim.x + threadIdx.x;
    if (e >= NNZ_CNT) return;
    int r = rows[e];
    int pos = atomicAdd(&cursor[r], 1);
    ep[pos] = make_int2(cols[e], __float_as_int(v[e]));
}

// Pass 2 gather v3: one wave per row; lane owns outputs (lane) and (lane+64),
// which share the same wav value. Unroll x4 for memory-level parallelism.
__global__ __launch_bounds__(256) void gather2_kernel(const int* __restrict__ offsets,
                                                      const int2* __restrict__ ep,
                                                      const float* __restrict__ LTx,
                                                      const float* __restrict__ wav,
                                                      float* __restrict__ out) {
    int wave = (int)(((long long)blockIdx.x * blockDim.x + threadIdx.x) >> 6);
    if (wave >= N_NODES) return;
    int lane = threadIdx.x & 63;
    int r = wave;
    int d0 = lane >> 3;        // 0..7
    int f  = lane & 7;         // 0..7
    int d1 = d0 + 8;           // 8..15
    int start = offsets[r];
    int end   = offsets[r + 1];
    float acc0 = 0.f, acc1 = 0.f;
    int i = start;
    for (; i + 4 <= end; i += 4) {
        int2 e0 = ep[i], e1 = ep[i + 1], e2 = ep[i + 2], e3 = ep[i + 3];
        float w0 = wav[(size_t)e0.x * NFILT + f];
        float w1 = wav[(size_t)e1.x * NFILT + f];
        float w2 = wav[(size_t)e2.x * NFILT + f];
        float w3 = wav[(size_t)e3.x * NFILT + f];
        float l00 = LTx[(size_t)e0.x * D_DIM + d0], l01 = LTx[(size_t)e0.x * D_DIM + d1];
        float l10 = LTx[(size_t)e1.x * D_DIM + d0], l11 = LTx[(size_t)e1.x * D_DIM + d1];
        float l20 = LTx[(size_t)e2.x * D_DIM + d0], l21 = LTx[(size_t)e2.x * D_DIM + d1];
        float l30 = LTx[(size_t)e3.x * D_DIM + d0], l31 = LTx[(size_t)e3.x * D_DIM + d1];
        float vw0 = __int_as_float(e0.y) * w0;
        float vw1 = __int_as_float(e1.y) * w1;
        float vw2 = __int_as_float(e2.y) * w2;
        float vw3 = __int_as_float(e3.y) * w3;
        acc0 = fmaf(vw0, l00, acc0); acc1 = fmaf(vw0, l01, acc1);
        acc0 = fmaf(vw1, l10, acc0); acc1 = fmaf(vw1, l11, acc1);
        acc0 = fmaf(vw2, l20, acc0); acc1 = fmaf(vw2, l21, acc1);
        acc0 = fmaf(vw3, l30, acc0); acc1 = fmaf(vw3, l31, acc1);
    }
    for (; i < end; ++i) {
        int2 e = ep[i];
        float w = wav[(size_t)e.x * NFILT + f];
        float vw = __int_as_float(e.y) * w;
        acc0 = fmaf(vw, LTx[(size_t)e.x * D_DIM + d0], acc0);
        acc1 = fmaf(vw, LTx[(size_t)e.x * D_DIM + d1], acc1);
    }
    out[(size_t)r * KOUT + lane]      = acc0;
    out[(size_t)r * KOUT + 64 + lane] = acc1;
}

extern "C" void kernel_launch(void* const* d_in, const int* in_sizes, int n_in,
                              void* d_out, int out_size, void* d_ws, size_t ws_size,
                              hipStream_t stream) {
    const float* x      = (const float*)d_in[0];
    const int*   L_rows = (const int*)  d_in[1];
    const int*   L_cols = (const int*)  d_in[2];
    const float* L_v    = (const float*)d_in[3];
    const float* eig    = (const float*)d_in[4];
    float* out = (float*)d_out;

    // workspace layout (ints/floats are 4B); keep ep 8-byte aligned
    float* LTx       = (float*)d_ws;                          // [N*16]
    float* wav       = LTx + (size_t)N_NODES * D_DIM;         // [N*8]
    int*   counts    = (int*)(wav + (size_t)N_NODES * NFILT); // [N]
    int*   offsets   = counts + N_NODES;                      // [N+1]
    int*   cursor    = offsets + N_NODES + 1;                 // [N]
    int*   blocksums = cursor + N_NODES;                      // [256]
    int*   blockoffs = blocksums + 256;                       // [256]
    size_t ep_off    = (size_t)(blockoffs + 256 - (int*)d_ws);
    ep_off = (ep_off + 1) & ~(size_t)1;                       // even -> 8B aligned
    int2*  ep        = (int2*)((int*)d_ws + ep_off);          // [NNZ] packed {col, val}

    hipMemsetAsync(LTx, 0, (size_t)N_NODES * D_DIM * sizeof(float), stream);
    hipMemsetAsync(counts, 0, (size_t)N_NODES * sizeof(int), stream);

    wav_kernel<<<(N_NODES + 255) / 256, 256, 0, stream>>>(eig, wav);

    hist_kernel<<<(NNZ_CNT + 255) / 256, 256, 0, stream>>>(L_rows, counts);
    scan1_kernel<<<SCAN_NBLK, SCAN_BLOCK, 0, stream>>>(counts, offsets, blocksums);
    scan2_kernel<<<1, 256, 0, stream>>>(blocksums, blockoffs);
    scan3_kernel<<<SCAN_NBLK, SCAN_BLOCK, 0, stream>>>(offsets, blockoffs, cursor);
    permute_kernel<<<(NNZ_CNT + 255) / 256, 256, 0, stream>>>(L_rows, L_cols, L_v, cursor, ep);

    {
        long long total = (long long)NNZ_CNT * D_DIM;
        scatter1_kernel<<<(int)((total + 255) / 256), 256, 0, stream>>>(x, L_rows, L_cols, L_v, LTx);
    }
    {
        long long threads = (long long)N_NODES * 64;   // one wave per row
        gather2_kernel<<<(int)((threads + 255) / 256), 256, 0, stream>>>(offsets, ep, LTx, wav, out);
    }
}